// Round 3
// baseline (681.289 us; speedup 1.0000x reference)
//
#include <hip/hip_runtime.h>

// NCE loss: N=4096, E=1024, V=50257, K=25, NORM_TERM=9.0
// loss = -sum_n [ log(p0/(p0+25*pn_t)) + sum_k log(25*pn_k/(pk+25*pn_k)) ] / N
// p_j = exp(bias[idx] + dot(x[n], W[idx]) - 9).
//
// Structure (frozen from round-2, measured 312.0 us total window):
// one 512-thread block (8 waves) per sample; waves 0,1 own 4 rows, waves
// 2..7 own 3 rows (j = wave + 8*jj covers 0..25). Two-phase per wave:
// issue all vector loads, then FMA. bias/noise prefetched wave-uniform.
//
// Round-3 change: finalize fused into the main kernel via last-block
// pattern (device-scope counter + threadfence + agent-scope atomic loads)
// -> one fewer dispatch per iteration. Workspace: 128 bucket floats +
// 1 uint counter = 516 B, memset 1 KB (hard contract: <=1 KB, round-1's
// 16 KB write crashed the container).
//
// Evidence note: harness poison fills (~2 x 121 us at 85% HBM peak) plus
// ~60-65 us main kernel account for the ~312 us window; occupancy probes
// (2 vs 4 waves/SIMD) were null, so the gather is service-rate-bound,
// not latency-bound.

#define NN 4096
#define EE 1024
#define KK 25
#define NBUCKET 128

__device__ __forceinline__ void fma4(float4& a, const float4& p, const float4& q) {
    a.x += p.x * q.x; a.y += p.y * q.y; a.z += p.z * q.z; a.w += p.w * q.w;
}

__global__ __launch_bounds__(512, 4) void nce_main_kernel(
    const float* __restrict__ x,
    const int* __restrict__ target,
    const int* __restrict__ noise_idx,
    const float* __restrict__ weight,
    const float* __restrict__ bias,
    const float* __restrict__ noise,
    float* __restrict__ ws,
    float* __restrict__ out)
{
    float* buckets = ws;                               // [NBUCKET]
    unsigned* counter = (unsigned*)(ws + NBUCKET);     // [1]

    const int n = blockIdx.x;
    const int wave = threadIdx.x >> 6;   // 0..7
    const int lane = threadIdx.x & 63;
    const int nj = (wave < 2) ? 4 : 3;   // rows per wave: 4,4,3,3,3,3,3,3 = 26

    // ---- phase 0: wave-uniform index loads (scalar), bias/noise prefetch ----
    int rows[4];
#pragma unroll
    for (int jj = 0; jj < 4; ++jj) {
        const int j = wave + (jj << 3);  // 0..25 for active jj
        rows[jj] = (jj < nj) ? ((j == 0) ? target[n] : noise_idx[n * KK + (j - 1)])
                             : 0;
    }
    float bv[4], nv[4];
#pragma unroll
    for (int jj = 0; jj < 4; ++jj) {
        bv[jj] = bias[rows[jj]];   // wave-uniform -> scalar loads, overlap with
        nv[jj] = noise[rows[jj]];  // the weight vector loads below
    }

    // ---- phase 1: issue ALL vector loads (4 x + 12/16 weight dwordx4) ----
    const float4* x4 = (const float4*)(x + (size_t)n * EE);
    float4 xr[4];
#pragma unroll
    for (int p = 0; p < 4; ++p) xr[p] = x4[(p << 6) + lane];

    float4 wr[4][4];
#pragma unroll
    for (int jj = 0; jj < 3; ++jj) {
        const float4* w4 = (const float4*)(weight + (size_t)rows[jj] * EE);
#pragma unroll
        for (int p = 0; p < 4; ++p) wr[jj][p] = w4[(p << 6) + lane];
    }
    if (nj == 4) {  // wave-uniform branch, waves 0,1 only
        const float4* w4 = (const float4*)(weight + (size_t)rows[3] * EE);
#pragma unroll
        for (int p = 0; p < 4; ++p) wr[3][p] = w4[(p << 6) + lane];
    }

    // ---- phase 2: FMAs ----
    float sacc[4];
#pragma unroll
    for (int jj = 0; jj < 3; ++jj) {
        float4 a = make_float4(0.f, 0.f, 0.f, 0.f);
#pragma unroll
        for (int p = 0; p < 4; ++p) fma4(a, xr[p], wr[jj][p]);
        sacc[jj] = (a.x + a.y) + (a.z + a.w);
    }
    sacc[3] = 0.f;
    if (nj == 4) {
        float4 a = make_float4(0.f, 0.f, 0.f, 0.f);
#pragma unroll
        for (int p = 0; p < 4; ++p) fma4(a, xr[p], wr[3][p]);
        sacc[3] = (a.x + a.y) + (a.z + a.w);
    }

    // ---- phase 3: butterfly reductions (3 or 4 independent chains) ----
#pragma unroll
    for (int jj = 0; jj < 3; ++jj) {
#pragma unroll
        for (int off = 32; off > 0; off >>= 1)
            sacc[jj] += __shfl_xor(sacc[jj], off);
    }
    if (nj == 4) {
#pragma unroll
        for (int off = 32; off > 0; off >>= 1)
            sacc[3] += __shfl_xor(sacc[3], off);
    }

    // ---- phase 4: per-wave epilogue, block reduce, one bucket atomic ----
    __shared__ float wpart[8];
    __shared__ int isLast;
    if (lane == 0) {
        float part = 0.0f;
#pragma unroll
        for (int jj = 0; jj < 4; ++jj) {
            if (jj < nj) {
                const float logit = sacc[jj] + bv[jj];
                const float p = expf(logit - 9.0f);
                const float pn25 = 25.0f * nv[jj];
                part += (wave == 0 && jj == 0) ? logf(p / (p + pn25))
                                               : logf(pn25 / (p + pn25));
            }
        }
        wpart[wave] = part;
    }
    __syncthreads();
    if (threadIdx.x == 0) {
        float t = 0.f;
#pragma unroll
        for (int w = 0; w < 8; ++w) t += wpart[w];
        atomicAdd(&buckets[n & (NBUCKET - 1)], -t);
        __threadfence();  // bucket add visible before counter tick
        unsigned old = __hip_atomic_fetch_add(counter, 1u, __ATOMIC_ACQ_REL,
                                              __HIP_MEMORY_SCOPE_AGENT);
        isLast = (old == NN - 1);
    }
    __syncthreads();

    // ---- phase 5: last block finalizes (replaces separate kernel) ----
    if (isLast && threadIdx.x < 64) {
        float acc = __hip_atomic_load(&buckets[threadIdx.x], __ATOMIC_RELAXED,
                                      __HIP_MEMORY_SCOPE_AGENT)
                  + __hip_atomic_load(&buckets[threadIdx.x + 64], __ATOMIC_RELAXED,
                                      __HIP_MEMORY_SCOPE_AGENT);
#pragma unroll
        for (int off = 32; off > 0; off >>= 1)
            acc += __shfl_xor(acc, off);
        if (threadIdx.x == 0)
            out[0] = acc / (float)NN;
    }
}

extern "C" void kernel_launch(void* const* d_in, const int* in_sizes, int n_in,
                              void* d_out, int out_size, void* d_ws, size_t ws_size,
                              hipStream_t stream) {
    const float* x        = (const float*)d_in[0];
    const int*   target   = (const int*)d_in[1];
    const int*   noiseIdx = (const int*)d_in[2];
    const float* weight   = (const float*)d_in[3];
    const float* bias     = (const float*)d_in[4];
    const float* noise    = (const float*)d_in[5];
    float* out = (float*)d_out;
    float* ws  = (float*)d_ws;  // 128 buckets + 1 counter = 516 B used

    hipMemsetAsync(ws, 0, 1024, stream);  // zero buckets + counter, 1 KB contract
    nce_main_kernel<<<NN, 512, 0, stream>>>(x, target, noiseIdx, weight, bias,
                                            noise, ws, out);
}

// Round 4
// 308.872 us; speedup vs baseline: 2.2057x; 2.2057x over previous
//
#include <hip/hip_runtime.h>

// NCE loss: N=4096, E=1024, V=50257, K=25, NORM_TERM=9.0
// loss = -sum_n [ log(p0/(p0+25*pn_t)) + sum_k log(25*pn_k/(pk+25*pn_k)) ] / N
// p_j = exp(bias[idx] + dot(x[n], W[idx]) - 9).
//
// REVERT to the round-2 kernel (measured 312.0 us, passed). Round-3's fused
// finalize (per-block __threadfence + ACQ_REL same-address counter atomic)
// serialized 4096 blocks -> main kernel 468 us even with warm cache
// (replay FETCH~0 still 466 us) -> total 681 us. Reverted.
//
// Known decomposition of the 312 us window (from round-3 counters):
//   ~242 us  harness poison fills (2 x 121 us @ 85% HBM peak, untouchable)
//   ~65 us   main kernel: FETCH_SIZE 225 MB ~= unique footprint (no over-
//            fetch); random 4KB-row gather at ~3.3 TB/s effective
//   ~5 us    memset + finalize + dispatch overhead
//
// Structure: one 512-thread block (8 waves) per sample; waves 0,1 own 4 rows,
// waves 2..7 own 3 rows (j = wave + 8*jj covers 0..25). bias/noise prefetched
// wave-uniform. Per-block partial -> one atomicAdd into 256 spread buckets
// (16 adds/bucket). Workspace: 1 KB hard contract (round-1's 16 KB write
// crashed the container).

#define NN 4096
#define EE 1024
#define KK 25
#define NBUCKET 256

__device__ __forceinline__ void fma4(float4& a, const float4& p, const float4& q) {
    a.x += p.x * q.x; a.y += p.y * q.y; a.z += p.z * q.z; a.w += p.w * q.w;
}

__global__ __launch_bounds__(512, 4) void nce_main_kernel(
    const float* __restrict__ x,
    const int* __restrict__ target,
    const int* __restrict__ noise_idx,
    const float* __restrict__ weight,
    const float* __restrict__ bias,
    const float* __restrict__ noise,
    float* __restrict__ buckets)
{
    const int n = blockIdx.x;
    const int wave = threadIdx.x >> 6;   // 0..7
    const int lane = threadIdx.x & 63;
    const int nj = (wave < 2) ? 4 : 3;   // rows per wave: 4,4,3,3,3,3,3,3 = 26

    // ---- phase 0: wave-uniform index loads (scalar), bias/noise prefetch ----
    int rows[4];
#pragma unroll
    for (int jj = 0; jj < 4; ++jj) {
        const int j = wave + (jj << 3);  // 0..25 for active jj
        rows[jj] = (jj < nj) ? ((j == 0) ? target[n] : noise_idx[n * KK + (j - 1)])
                             : 0;
    }
    float bv[4], nv[4];
#pragma unroll
    for (int jj = 0; jj < 4; ++jj) {
        bv[jj] = bias[rows[jj]];   // wave-uniform -> scalar loads, overlap with
        nv[jj] = noise[rows[jj]];  // the weight vector loads below
    }

    // ---- phase 1: issue ALL vector loads (4 x + 12/16 weight dwordx4) ----
    const float4* x4 = (const float4*)(x + (size_t)n * EE);
    float4 xr[4];
#pragma unroll
    for (int p = 0; p < 4; ++p) xr[p] = x4[(p << 6) + lane];

    float4 wr[4][4];
#pragma unroll
    for (int jj = 0; jj < 3; ++jj) {
        const float4* w4 = (const float4*)(weight + (size_t)rows[jj] * EE);
#pragma unroll
        for (int p = 0; p < 4; ++p) wr[jj][p] = w4[(p << 6) + lane];
    }
    if (nj == 4) {  // wave-uniform branch, waves 0,1 only
        const float4* w4 = (const float4*)(weight + (size_t)rows[3] * EE);
#pragma unroll
        for (int p = 0; p < 4; ++p) wr[3][p] = w4[(p << 6) + lane];
    }

    // ---- phase 2: FMAs ----
    float sacc[4];
#pragma unroll
    for (int jj = 0; jj < 3; ++jj) {
        float4 a = make_float4(0.f, 0.f, 0.f, 0.f);
#pragma unroll
        for (int p = 0; p < 4; ++p) fma4(a, xr[p], wr[jj][p]);
        sacc[jj] = (a.x + a.y) + (a.z + a.w);
    }
    sacc[3] = 0.f;
    if (nj == 4) {
        float4 a = make_float4(0.f, 0.f, 0.f, 0.f);
#pragma unroll
        for (int p = 0; p < 4; ++p) fma4(a, xr[p], wr[3][p]);
        sacc[3] = (a.x + a.y) + (a.z + a.w);
    }

    // ---- phase 3: butterfly reductions (3 or 4 independent chains) ----
#pragma unroll
    for (int jj = 0; jj < 3; ++jj) {
#pragma unroll
        for (int off = 32; off > 0; off >>= 1)
            sacc[jj] += __shfl_xor(sacc[jj], off);
    }
    if (nj == 4) {
#pragma unroll
        for (int off = 32; off > 0; off >>= 1)
            sacc[3] += __shfl_xor(sacc[3], off);
    }

    // ---- phase 4: per-wave epilogue (pure ALU), block reduce, one atomic ----
    __shared__ float wpart[8];
    if (lane == 0) {
        float part = 0.0f;
#pragma unroll
        for (int jj = 0; jj < 4; ++jj) {
            if (jj < nj) {
                const float logit = sacc[jj] + bv[jj];
                const float p = expf(logit - 9.0f);
                const float pn25 = 25.0f * nv[jj];
                part += (wave == 0 && jj == 0) ? logf(p / (p + pn25))
                                               : logf(pn25 / (p + pn25));
            }
        }
        wpart[wave] = part;
    }
    __syncthreads();
    if (threadIdx.x == 0) {
        float t = 0.f;
#pragma unroll
        for (int w = 0; w < 8; ++w) t += wpart[w];
        atomicAdd(&buckets[n & (NBUCKET - 1)], -t);
    }
}

__global__ __launch_bounds__(64) void nce_finalize_kernel(
    const float* __restrict__ buckets, float* __restrict__ out)
{
    float acc = buckets[threadIdx.x] + buckets[threadIdx.x + 64]
              + buckets[threadIdx.x + 128] + buckets[threadIdx.x + 192];
#pragma unroll
    for (int off = 32; off > 0; off >>= 1)
        acc += __shfl_xor(acc, off);
    if (threadIdx.x == 0)
        out[0] = acc / (float)NN;
}

extern "C" void kernel_launch(void* const* d_in, const int* in_sizes, int n_in,
                              void* d_out, int out_size, void* d_ws, size_t ws_size,
                              hipStream_t stream) {
    const float* x        = (const float*)d_in[0];
    const int*   target   = (const int*)d_in[1];
    const int*   noiseIdx = (const int*)d_in[2];
    const float* weight   = (const float*)d_in[3];
    const float* bias     = (const float*)d_in[4];
    const float* noise    = (const float*)d_in[5];
    float* out = (float*)d_out;
    float* buckets = (float*)d_ws;  // NBUCKET floats = 1 KB, verified footprint

    hipMemsetAsync(buckets, 0, NBUCKET * sizeof(float), stream);
    nce_main_kernel<<<NN, 512, 0, stream>>>(x, target, noiseIdx, weight, bias, noise, buckets);
    nce_finalize_kernel<<<1, 64, 0, stream>>>(buckets, out);
}